// Round 3
// baseline (87.651 us; speedup 1.0000x reference)
//
#include <hip/hip_runtime.h>

#define EPS 1e-3f

typedef float f32x4 __attribute__((ext_vector_type(4)));
typedef float f4    __attribute__((ext_vector_type(4)));
typedef short short8 __attribute__((ext_vector_type(8)));

__device__ __forceinline__ unsigned short f2bf(float f) {
    unsigned u = __float_as_uint(f);
    u += 0x7FFFu + ((u >> 16) & 1u);   // round-to-nearest-even
    return (unsigned short)(u >> 16);
}
__device__ __forceinline__ float bf2f(unsigned s) {
    return __uint_as_float(s << 16);
}

// ---------------------------------------------------------------------------
// Prep: fold BN1/BN2 into attention weights, transpose all weights to bf16
// ---------------------------------------------------------------------------
__global__ void prep_kernel(const float* __restrict__ w3,
                            const float* __restrict__ g1, const float* __restrict__ be1,
                            const float* __restrict__ m1, const float* __restrict__ v1,
                            const float* __restrict__ wa1, const float* __restrict__ ba1,
                            const float* __restrict__ g2, const float* __restrict__ be2,
                            const float* __restrict__ m2, const float* __restrict__ v2,
                            const float* __restrict__ wa2, const float* __restrict__ ba2,
                            unsigned short* __restrict__ w3T,
                            unsigned short* __restrict__ wa1T,
                            unsigned short* __restrict__ wa2T,
                            float* __restrict__ b_a1p, float* __restrict__ b_a2p)
{
    const int blk = blockIdx.x;
    const int tid = threadIdx.x;
    if (blk < 64) {
        #pragma unroll
        for (int i = 0; i < 4; ++i) {
            int f = blk * 4 + i;
            w3T[f * 256 + tid] = f2bf(w3[tid * 256 + f]);
        }
    } else if (blk < 96) {
        int a = blk - 64;
        int c = tid;
        float s1 = rsqrtf(v1[c] + EPS) * g1[c];
        float wv = wa1[c * 32 + a];
        wa1T[a * 256 + c] = f2bf(wv * s1);
        float part = (be1[c] - m1[c] * s1) * wv;
        __shared__ float red[4];
        #pragma unroll
        for (int off = 32; off > 0; off >>= 1) part += __shfl_down(part, off);
        if ((tid & 63) == 0) red[tid >> 6] = part;
        __syncthreads();
        if (tid == 0) b_a1p[a] = ba1[a] + red[0] + red[1] + red[2] + red[3];
    } else {
        int f = tid;
        float acc = ba2[f];
        #pragma unroll
        for (int a = 0; a < 32; ++a) {
            float s2 = rsqrtf(v2[a] + EPS) * g2[a];
            float wv = wa2[a * 256 + f];
            wa2T[f * 32 + a] = f2bf(wv * s2);
            acc += (be2[a] - m2[a] * s2) * wv;
        }
        b_a2p[f] = acc;
    }
}

// ---------------------------------------------------------------------------
// Fused main kernel. One block = one image row (b,h): 64 pixels, 256 ch.
// 8 waves. LDS 37.5 KB:
//   [0,32768)      rs: 3x3 box-sum bf16 [64px][256c] XOR-swizzled;
//                  reused after main GEMM as aw e-values bf16 [px][256f],
//                  addr = px*512 + ((f*2) ^ ((px&7)<<4))
//   [32768,37888)  a1 stash, per attention wave 1280 B (pitch 80)
//   [37888,38144)  invS: 64 f32 (1/softmax-denominator per px)
// Every wave does a 32-f slice of the main GEMM (accs[2][4], 32 VGPR).
// Waves 0-3 additionally run the attention path (2-pass online softmax,
// A-frags read from global x which is L2-hot).
// Final: o[px][f] = e*invS*(s + cnt*b3); each wave writes one full 128 B
// line per pixel (32 ch x 4 B) -> no write amplification.
// ---------------------------------------------------------------------------
__global__ __launch_bounds__(512, 6)
void fused_kernel(const float* __restrict__ x, const float* __restrict__ b3,
                  const unsigned short* __restrict__ w3T,
                  const unsigned short* __restrict__ wa1T,
                  const unsigned short* __restrict__ wa2T,
                  const float* __restrict__ b_a1p, const float* __restrict__ b_a2p,
                  float* __restrict__ out)
{
    __shared__ __align__(16) unsigned char lds[38400];

    const int tid = threadIdx.x;
    const int bid = blockIdx.x;
    // XCD-aware swizzle: 1024 blocks, 8 XCDs -> 128 consecutive rows per XCD
    const int swz = (bid & 7) * 128 + (bid >> 3);
    const int b = swz >> 6;
    const int h = swz & 63;

    const float* xrow = x + ((size_t)(b * 64 + h) * 64) * 256;
    const bool hm = (h > 0), hp = (h < 63);
    const f4* p0 = (const f4*)xrow;
    const f4* pm = (const f4*)(xrow - 64 * 256);
    const f4* pp = (const f4*)(xrow + 64 * 256);
    const f4 zero4 = {0.f, 0.f, 0.f, 0.f};

    // ---------------- phase 0: 3-row vertical sum -> rs (bf16) -------------
    #pragma unroll
    for (int j = 0; j < 8; ++j) {
        int v  = tid + j * 512;        // float4 index within the row (0..4095)
        int w  = v >> 6;
        int c4 = v & 63;
        f4 a0 = p0[v];
        f4 am = hm ? pm[v] : zero4;
        f4 ap = hp ? pp[v] : zero4;
        f4 s = a0 + am + ap;
        unsigned cb   = (unsigned)c4 * 8u;
        unsigned addr = (unsigned)w * 512u + (cb ^ (((unsigned)w & 7u) << 4));
        uint2 pr;
        pr.x = (unsigned)f2bf(s.x) | ((unsigned)f2bf(s.y) << 16);
        pr.y = (unsigned)f2bf(s.z) | ((unsigned)f2bf(s.w) << 16);
        *(uint2*)(lds + addr) = pr;
    }
    __syncthreads();

    // ---------------- phase 0.5: horizontal 3-tap sum in place -------------
    {
        const int w05 = tid >> 3;      // pixel 0..63
        const int cs  = tid & 7;       // channel eighth
        uint2 tv[8];
        #pragma unroll
        for (int j = 0; j < 8; ++j) {
            int c4 = cs * 8 + j;
            unsigned cb = (unsigned)c4 * 8u;
            f4 sum = zero4;
            #pragma unroll
            for (int dw = -1; dw <= 1; ++dw) {
                int rw = w05 + dw;
                if (rw >= 0 && rw < 64) {
                    unsigned ad = (unsigned)rw * 512u +
                                  (cb ^ (((unsigned)rw & 7u) << 4));
                    uint2 q = *(const uint2*)(lds + ad);
                    sum.x += bf2f(q.x & 0xffffu);
                    sum.y += bf2f(q.x >> 16);
                    sum.z += bf2f(q.y & 0xffffu);
                    sum.w += bf2f(q.y >> 16);
                }
            }
            uint2 pk;
            pk.x = (unsigned)f2bf(sum.x) | ((unsigned)f2bf(sum.y) << 16);
            pk.y = (unsigned)f2bf(sum.z) | ((unsigned)f2bf(sum.w) << 16);
            tv[j] = pk;
        }
        __syncthreads();
        #pragma unroll
        for (int j = 0; j < 8; ++j) {
            int c4 = cs * 8 + j;
            unsigned cb = (unsigned)c4 * 8u;
            unsigned ad = (unsigned)w05 * 512u +
                          (cb ^ (((unsigned)w05 & 7u) << 4));
            *(uint2*)(lds + ad) = tv[j];
        }
        __syncthreads();
    }

    const int wv   = tid >> 6;
    const int lane = tid & 63;
    const int cl   = lane & 15;
    const int lkg  = lane >> 4;
    const int F0   = wv * 32;

    // ---------------- main GEMM: every wave does 32 f x 64 px --------------
    f32x4 accs[2][4];
    #pragma unroll
    for (int ft = 0; ft < 2; ++ft)
        #pragma unroll
        for (int pt = 0; pt < 4; ++pt) accs[ft][pt] = (f32x4){0,0,0,0};

    for (int kk = 0; kk < 8; ++kk) {
        short8 afr[2];
        #pragma unroll
        for (int ft = 0; ft < 2; ++ft)
            afr[ft] = *(const short8*)(w3T + ((F0 + ft * 16 + cl) * 256 + kk * 32 + lkg * 8));
        short8 bfr[4];
        #pragma unroll
        for (int pt = 0; pt < 4; ++pt) {
            int px = pt * 16 + cl;
            unsigned cb = (unsigned)kk * 64u + (unsigned)lkg * 16u;
            bfr[pt] = *(const short8*)(lds + (unsigned)px * 512u +
                                       (cb ^ (((unsigned)px & 7u) << 4)));
        }
        #pragma unroll
        for (int ft = 0; ft < 2; ++ft)
            #pragma unroll
            for (int pt = 0; pt < 4; ++pt)
                accs[ft][pt] = __builtin_amdgcn_mfma_f32_16x16x32_bf16(afr[ft], bfr[pt], accs[ft][pt], 0, 0, 0);
    }

    __syncthreads();   // all rs reads done; region 0 becomes aw

    // ---------------- attention path (waves 0-3) ---------------------------
    if (wv < 4) {
        const int pxb  = wv * 16;
        const int px   = pxb + cl;
        const float* xr = xrow + px * 256;     // this lane's pixel row (L2-hot)

        // --- GEMM1: a1 = relu(x_bn @ wa1'), A-frags from global f32 --------
        f32x4 acc1[2];
        acc1[0] = (f32x4){0,0,0,0};
        acc1[1] = (f32x4){0,0,0,0};
        #pragma unroll
        for (int kk = 0; kk < 8; ++kk) {
            f4 u0 = *(const f4*)(xr + kk * 32 + lkg * 8);
            f4 u1 = *(const f4*)(xr + kk * 32 + lkg * 8 + 4);
            short8 afr;
            afr[0] = (short)f2bf(u0.x); afr[1] = (short)f2bf(u0.y);
            afr[2] = (short)f2bf(u0.z); afr[3] = (short)f2bf(u0.w);
            afr[4] = (short)f2bf(u1.x); afr[5] = (short)f2bf(u1.y);
            afr[6] = (short)f2bf(u1.z); afr[7] = (short)f2bf(u1.w);
            #pragma unroll
            for (int t = 0; t < 2; ++t) {
                short8 bfr = *(const short8*)(wa1T + ((t * 16 + cl) * 256 + kk * 32 + lkg * 8));
                acc1[t] = __builtin_amdgcn_mfma_f32_16x16x32_bf16(afr, bfr, acc1[t], 0, 0, 0);
            }
        }
        // stash a1 bf16, per-wave region, pitch 80 B
        const unsigned a1base = 32768u + (unsigned)wv * 1280u;
        #pragma unroll
        for (int t = 0; t < 2; ++t) {
            int a = t * 16 + cl;
            float bb = b_a1p[a];
            #pragma unroll
            for (int r = 0; r < 4; ++r) {
                float vv = acc1[t][r] + bb;
                vv = vv > 0.f ? vv : 0.f;
                int pxl = lkg * 4 + r;
                *(unsigned short*)(lds + a1base + pxl * 80 + a * 2) = f2bf(vv);
            }
        }
        asm volatile("s_waitcnt lgkmcnt(0)" ::: "memory");
        __builtin_amdgcn_sched_barrier(0);

        // --- GEMM2 (swapped) 2-pass online softmax -------------------------
        short8 a1f = *(const short8*)(lds + a1base + cl * 80 + lkg * 16);
        // pass 1: running max (relu output >= 0, init 0)
        float mx = 0.f;
        #pragma unroll
        for (int t = 0; t < 16; ++t) {
            short8 a2w = *(const short8*)(wa2T + ((t * 16 + cl) * 32 + lkg * 8));
            f32x4 z = {0,0,0,0};
            f32x4 tl = __builtin_amdgcn_mfma_f32_16x16x32_bf16(a2w, a1f, z, 0, 0, 0);
            f4 bb = *(const f4*)(b_a2p + t * 16 + lkg * 4);
            #pragma unroll
            for (int r = 0; r < 4; ++r) {
                float vv = tl[r] + bb[r];
                mx = fmaxf(mx, vv);
            }
        }
        mx = fmaxf(mx, __shfl_xor(mx, 16));
        mx = fmaxf(mx, __shfl_xor(mx, 32));
        // pass 2: e = exp(relu(att)-mx) -> aw LDS (bf16), accumulate sum
        float sm = 0.f;
        #pragma unroll
        for (int t = 0; t < 16; ++t) {
            short8 a2w = *(const short8*)(wa2T + ((t * 16 + cl) * 32 + lkg * 8));
            f32x4 z = {0,0,0,0};
            f32x4 tl = __builtin_amdgcn_mfma_f32_16x16x32_bf16(a2w, a1f, z, 0, 0, 0);
            f4 bb = *(const f4*)(b_a2p + t * 16 + lkg * 4);
            float e[4];
            #pragma unroll
            for (int r = 0; r < 4; ++r) {
                float vv = tl[r] + bb[r];
                vv = vv > 0.f ? vv : 0.f;
                e[r] = __expf(vv - mx);
                sm += e[r];
            }
            uint2 pk;
            pk.x = (unsigned)f2bf(e[0]) | ((unsigned)f2bf(e[1]) << 16);
            pk.y = (unsigned)f2bf(e[2]) | ((unsigned)f2bf(e[3]) << 16);
            unsigned f2 = (unsigned)(t * 32 + lkg * 8);   // f0*2 bytes
            unsigned ad = (unsigned)px * 512u + (f2 ^ (((unsigned)px & 7u) << 4));
            *(uint2*)(lds + ad) = pk;
        }
        sm += __shfl_xor(sm, 16);
        sm += __shfl_xor(sm, 32);
        if (lkg == 0) *(float*)(lds + 37888 + px * 4) = 1.f / sm;
    }

    __syncthreads();   // aw + invS ready

    // ---------------- final: o = e * invS * (s + cnt*b3) -------------------
    const int rh = (h == 0 || h == 63) ? 2 : 3;
    const size_t obase = ((size_t)(b * 64 + h) * 64) * 256;
    f4 b3v[2];
    #pragma unroll
    for (int ft = 0; ft < 2; ++ft)
        b3v[ft] = *(const f4*)(b3 + F0 + ft * 16 + lkg * 4);
    #pragma unroll
    for (int pt = 0; pt < 4; ++pt) {
        int px = pt * 16 + cl;
        float is = *(const float*)(lds + 37888 + px * 4);
        float cnt = (float)(rh * ((px == 0 || px == 63) ? 2 : 3));
        #pragma unroll
        for (int ft = 0; ft < 2; ++ft) {
            int f0 = F0 + ft * 16 + lkg * 4;
            unsigned ad = (unsigned)px * 512u +
                          (((unsigned)f0 * 2u) ^ (((unsigned)px & 7u) << 4));
            uint2 ev = *(const uint2*)(lds + ad);
            f4 o;
            o.x = bf2f(ev.x & 0xffffu) * is * (accs[ft][pt][0] + cnt * b3v[ft].x);
            o.y = bf2f(ev.x >> 16)     * is * (accs[ft][pt][1] + cnt * b3v[ft].y);
            o.z = bf2f(ev.y & 0xffffu) * is * (accs[ft][pt][2] + cnt * b3v[ft].z);
            o.w = bf2f(ev.y >> 16)     * is * (accs[ft][pt][3] + cnt * b3v[ft].w);
            *(f4*)(out + obase + (size_t)px * 256 + f0) = o;
        }
    }
}

extern "C" void kernel_launch(void* const* d_in, const int* in_sizes, int n_in,
                              void* d_out, int out_size, void* d_ws, size_t ws_size,
                              hipStream_t stream)
{
    const float* x   = (const float*)d_in[0];
    const float* w3  = (const float*)d_in[1];
    const float* b3  = (const float*)d_in[2];
    const float* g1  = (const float*)d_in[3];
    const float* be1 = (const float*)d_in[4];
    const float* m1  = (const float*)d_in[5];
    const float* v1  = (const float*)d_in[6];
    const float* wa1 = (const float*)d_in[7];
    const float* ba1 = (const float*)d_in[8];
    const float* g2  = (const float*)d_in[9];
    const float* be2 = (const float*)d_in[10];
    const float* m2  = (const float*)d_in[11];
    const float* v2  = (const float*)d_in[12];
    const float* wa2 = (const float*)d_in[13];
    const float* ba2 = (const float*)d_in[14];

    unsigned char* ws = (unsigned char*)d_ws;
    unsigned short* w3T   = (unsigned short*)(ws);
    unsigned short* wa1T  = (unsigned short*)(ws + 131072);
    unsigned short* wa2T  = (unsigned short*)(ws + 147456);
    float*          b_a1p = (float*)(ws + 163840);
    float*          b_a2p = (float*)(ws + 163968);

    hipLaunchKernelGGL(prep_kernel, dim3(97), dim3(256), 0, stream,
                       w3, g1, be1, m1, v1, wa1, ba1, g2, be2, m2, v2, wa2, ba2,
                       w3T, wa1T, wa2T, b_a1p, b_a2p);
    hipLaunchKernelGGL(fused_kernel, dim3(1024), dim3(512), 0, stream,
                       x, b3, w3T, wa1T, wa2T, b_a1p, b_a2p, (float*)d_out);
}